// Round 3
// baseline (1059.004 us; speedup 1.0000x reference)
//
#include <hip/hip_runtime.h>
#include <hip/hip_bf16.h>
#include <stdint.h>

// ---------------------------------------------------------------------------
// PropagationRWKV: LN -> (k,v,r) GEMM -> channel-decay scan (decoupled
// lookback, fused) -> y GEMM -> out.  B=8, N=16384, C=256. M = 131072 rows.
// bf16 MFMA 16x16x32, swapped-operand (Ct) epilogue, XCD-aware grid swizzle.
// ---------------------------------------------------------------------------

typedef __attribute__((ext_vector_type(8))) short short8;
typedef __attribute__((ext_vector_type(4))) float f32x4;

static __device__ __forceinline__ unsigned short f2bf(float f) {
  __hip_bfloat16 h = __float2bfloat16(f);
  return *reinterpret_cast<unsigned short*>(&h);
}
static __device__ __forceinline__ float bf2f(unsigned short u) {
  unsigned int v = ((unsigned int)u) << 16;
  float f;
  __builtin_memcpy(&f, &v, 4);
  return f;
}

// ---------------------------------------------------------------------------
// K1: fused LayerNorm (blocks 0..32767), weight cvt (32768..33791),
// flag zeroing (33792).  One launch instead of three.
// ---------------------------------------------------------------------------
__global__ void k1_fused(const float* __restrict__ x,
                         const float* __restrict__ lnw,
                         const float* __restrict__ lnb,
                         const float* __restrict__ Wk,
                         const float* __restrict__ Wv,
                         const float* __restrict__ Wr,
                         const float* __restrict__ Wo,
                         unsigned short* __restrict__ xn,
                         unsigned short* __restrict__ Wkvr,
                         unsigned short* __restrict__ Wob,
                         int* __restrict__ flags) {
  const int bid = blockIdx.x;
  if (bid < 32768) {
    // LayerNorm: one wave per row, 4 rows per block.
    const int wv = threadIdx.x >> 6;
    const int ln = threadIdx.x & 63;
    const size_t row = (size_t)bid * 4 + wv;
    const float4 v = reinterpret_cast<const float4*>(x)[row * 64 + ln];
    float s  = v.x + v.y + v.z + v.w;
    float sq = v.x * v.x + v.y * v.y + v.z * v.z + v.w * v.w;
#pragma unroll
    for (int off = 32; off; off >>= 1) {
      s  += __shfl_xor(s, off, 64);
      sq += __shfl_xor(sq, off, 64);
    }
    const float mu  = s * (1.0f / 256.0f);
    const float var = sq * (1.0f / 256.0f) - mu * mu;
    const float rs  = rsqrtf(var + 1e-5f);
    const float4 w4 = reinterpret_cast<const float4*>(lnw)[ln];
    const float4 b4 = reinterpret_cast<const float4*>(lnb)[ln];
    ushort4 o;
    o.x = f2bf((v.x - mu) * rs * w4.x + b4.x);
    o.y = f2bf((v.y - mu) * rs * w4.y + b4.y);
    o.z = f2bf((v.z - mu) * rs * w4.z + b4.z);
    o.w = f2bf((v.w - mu) * rs * w4.w + b4.w);
    reinterpret_cast<ushort4*>(xn)[row * 64 + ln] = o;
  } else if (bid < 33792) {
    const int idx = (bid - 32768) * 256 + threadIdx.x;
    if (idx < 768 * 256) {
      const int r = idx >> 8;
      const int c = idx & 255;
      const float* src = (r < 256) ? Wk : ((r < 512) ? Wv : Wr);
      Wkvr[idx] = f2bf(src[(r & 255) * 256 + c]);
    } else {
      const int j = idx - 768 * 256;
      Wob[j] = f2bf(Wo[j]);
    }
  } else {
    // zero 512 lookback flags (ws is poisoned before every launch)
    flags[threadIdx.x] = 0;
    flags[threadIdx.x + 256] = 0;
  }
}

// ---------------------------------------------------------------------------
// MFMA GEMM: C[m][n] = sum_k A[m][k] * Bt[n][k].
// 128x128 tile / block, 4 waves, 64x64 per wave (4x4 of 16x16x32 MFMA).
// Swapped-operand mfma (Ct fragments): lane holds 4 consecutive n per acc.
// XCD-aware grid: xcd = bid&7 owns m-tiles [xcd*128, xcd*128+128), n-slices
// innermost -> A-tile reuse inside one XCD's L2.
// EPI 0: split k/v/sigmoid(r) bf16 epilogue. EPI 1: fp32 out.
// ---------------------------------------------------------------------------
template <int EPI, int NY>
__global__ void gemm_bt(const unsigned short* __restrict__ A,
                        const unsigned short* __restrict__ Bt,
                        unsigned short* __restrict__ kbuf,
                        unsigned short* __restrict__ vbuf,
                        unsigned short* __restrict__ rbuf,
                        float* __restrict__ outf) {
  constexpr int K = 256;
  __shared__ unsigned short Als[128][64];  // 16 KiB, swizzled 16B chunks
  __shared__ unsigned short Bls[128][64];  // 16 KiB

  const int tid = threadIdx.x;
  const int wv = tid >> 6;
  const int ln = tid & 63;
  const int bid = blockIdx.x;
  const int xcd = bid & 7;
  const int j = bid >> 3;
  const int bm0 = (xcd * 128 + j / NY) * 128;
  const int bn0 = (j % NY) * 128;
  const int lq = ln >> 4;   // quad 0..3
  const int lm = ln & 15;

  f32x4 acc[4][4];
#pragma unroll
  for (int i = 0; i < 4; ++i)
#pragma unroll
    for (int jj = 0; jj < 4; ++jj) acc[i][jj] = (f32x4){0.f, 0.f, 0.f, 0.f};

  const int m0w = (wv >> 1) * 64;
  const int n0w = (wv & 1) * 64;

  const int srow = ln >> 3;              // 0..7 (row within 8-row group)
  const int schunk = (ln & 7) ^ srow;    // swizzled source chunk

  for (int kk0 = 0; kk0 < K; kk0 += 64) {
#pragma unroll
    for (int i = 0; i < 4; ++i) {
      const int rr = wv * 32 + i * 8;    // wave-uniform base row
      const unsigned short* gA = A + (size_t)(bm0 + rr + srow) * K + kk0 + schunk * 8;
      __builtin_amdgcn_global_load_lds(
          (const __attribute__((address_space(1))) void*)gA,
          (__attribute__((address_space(3))) void*)&Als[rr][0], 16, 0, 0);
      const unsigned short* gB = Bt + (size_t)(bn0 + rr + srow) * K + kk0 + schunk * 8;
      __builtin_amdgcn_global_load_lds(
          (const __attribute__((address_space(1))) void*)gB,
          (__attribute__((address_space(3))) void*)&Bls[rr][0], 16, 0, 0);
    }
    __syncthreads();
#pragma unroll
    for (int kk = 0; kk < 64; kk += 32) {
      short8 af[4], bfr[4];
      const int chunk = (kk >> 3) + lq;  // 0..3 or 4..7
#pragma unroll
      for (int t = 0; t < 4; ++t) {
        const int rowa = m0w + t * 16 + lm;
        af[t] = *reinterpret_cast<const short8*>(&Als[rowa][(chunk ^ (rowa & 7)) * 8]);
        const int rowb = n0w + t * 16 + lm;
        bfr[t] = *reinterpret_cast<const short8*>(&Bls[rowb][(chunk ^ (rowb & 7)) * 8]);
      }
#pragma unroll
      for (int mt = 0; mt < 4; ++mt)
#pragma unroll
        for (int nt = 0; nt < 4; ++nt)
          acc[mt][nt] = __builtin_amdgcn_mfma_f32_16x16x32_bf16(
              bfr[nt], af[mt], acc[mt][nt], 0, 0, 0);
    }
    __syncthreads();
  }

  // Epilogue (Ct layout): m = ...+lm, n_base = ...+lq*4, regs span n.
#pragma unroll
  for (int mt = 0; mt < 4; ++mt) {
    const int m_g = bm0 + m0w + mt * 16 + lm;
#pragma unroll
    for (int nt = 0; nt < 4; ++nt) {
      const int n_base = bn0 + n0w + nt * 16 + lq * 4;
      f32x4 a = acc[mt][nt];
      if (EPI == 0) {
        const int bufi = n_base >> 8;   // uniform within a 16-wide nt tile
        const int col = n_base & 255;
        unsigned short* dst = (bufi == 0) ? kbuf : ((bufi == 1) ? vbuf : rbuf);
        if (bufi == 2) {
#pragma unroll
          for (int r = 0; r < 4; ++r) a[r] = 1.0f / (1.0f + __expf(-a[r]));
        }
        ushort4 pk;
        pk.x = f2bf(a[0]); pk.y = f2bf(a[1]); pk.z = f2bf(a[2]); pk.w = f2bf(a[3]);
        *reinterpret_cast<ushort4*>(&dst[(size_t)m_g * 256 + col]) = pk;
      } else {
        float4 o = make_float4(a[0], a[1], a[2], a[3]);
        *reinterpret_cast<float4*>(&outf[(size_t)m_g * 256 + n_base]) = o;
      }
    }
  }
}

// ---------------------------------------------------------------------------
// Fused scan with decoupled lookback (rocPRIM pattern).
// 512 blocks; block blk covers 256 timesteps [blk*256, blk*256+256), all
// inside one batch (64 blocks/batch). 8 sub-chunks of 32 steps; thread
// (sub=t>>5, lane=t&31) owns 8 channels c0=lane*8 of its sub-chunk.
// Phase 1: local carries (short8 loads). Combine -> block aggregate.
// Phase 2: publish aggregate (flag 1), lookback walk, publish prefix (flag 2).
// Phase 3: recompute states from carry-in, y = r*(state+v) -> bf16 over k.
// ---------------------------------------------------------------------------
__global__ void scan_fused(unsigned short* __restrict__ k,
                           const unsigned short* __restrict__ v,
                           const unsigned short* __restrict__ r,
                           const float* __restrict__ td,
                           float* __restrict__ carryA,
                           float* __restrict__ prefixP,
                           int* __restrict__ flags) {
  __shared__ float lsP[8][256];   // sub-chunk partial carries
  __shared__ float lsS[8][256];   // per-sub starting states
  __shared__ int fstat;

  const int blk = blockIdx.x;
  const int jb = blk & 63;              // block index within batch
  const int tid = threadIdx.x;
  const int sub = tid >> 5;             // 0..7
  const int lane = tid & 31;
  const int c0 = lane * 8;

  float d[8];
#pragma unroll
  for (int jj = 0; jj < 8; ++jj) d[jj] = __expf(-fmaxf(td[c0 + jj], 0.0f));

  // ---- Phase 1: local carry over this thread's 32 steps
  const size_t base = ((size_t)blk * 256 + sub * 32) * 256 + c0;
  float s[8];
#pragma unroll
  for (int jj = 0; jj < 8; ++jj) s[jj] = 0.0f;
#pragma unroll 4
  for (int i = 0; i < 32; ++i) {
    short8 kv = *reinterpret_cast<const short8*>(k + base + (size_t)i * 256);
#pragma unroll
    for (int jj = 0; jj < 8; ++jj) s[jj] = s[jj] * d[jj] + bf2f((unsigned short)kv[jj]);
  }
#pragma unroll
  for (int jj = 0; jj < 8; ++jj) lsP[sub][c0 + jj] = s[jj];
  __syncthreads();

  // ---- Combine: thread tid = channel c. Aggregate over 8 subs.
  const float dc  = __expf(-fmaxf(td[tid], 0.0f));
  const float dB  = __expf(-fmaxf(td[tid], 0.0f) * 32.0f);   // d^32
  const float dS  = __expf(-fmaxf(td[tid], 0.0f) * 256.0f);  // d^256
  float a_blk = 0.0f;
#pragma unroll
  for (int s8 = 0; s8 < 8; ++s8) a_blk = dB * a_blk + lsP[s8][tid];

  float s_in_blk;
  if (jb == 0) {
    prefixP[(size_t)blk * 256 + tid] = a_blk;
    __threadfence();
    __syncthreads();
    if (tid == 0)
      __hip_atomic_store(&flags[blk], 2, __ATOMIC_RELEASE, __HIP_MEMORY_SCOPE_AGENT);
    s_in_blk = 0.0f;
  } else {
    carryA[(size_t)blk * 256 + tid] = a_blk;
    __threadfence();
    __syncthreads();
    if (tid == 0)
      __hip_atomic_store(&flags[blk], 1, __ATOMIC_RELEASE, __HIP_MEMORY_SCOPE_AGENT);
    // lookback walk
    float acc = 0.0f, w = 1.0f;
    int pred = blk - 1;
    for (;;) {
      if (tid == 0) {
        int f;
        do {
          f = __hip_atomic_load(&flags[pred], __ATOMIC_ACQUIRE, __HIP_MEMORY_SCOPE_AGENT);
          if (f == 0) __builtin_amdgcn_s_sleep(8);
        } while (f == 0);
        fstat = f;
      }
      __syncthreads();
      const int f = fstat;
      __threadfence();
      if (f == 2) {
        acc += w * prefixP[(size_t)pred * 256 + tid];
        break;
      }
      acc += w * carryA[(size_t)pred * 256 + tid];
      w *= dS;
      --pred;
      __syncthreads();
    }
    s_in_blk = acc;
    prefixP[(size_t)blk * 256 + tid] = dS * s_in_blk + a_blk;
    __threadfence();
    __syncthreads();
    if (tid == 0)
      __hip_atomic_store(&flags[blk], 2, __ATOMIC_RELEASE, __HIP_MEMORY_SCOPE_AGENT);
  }

  // ---- Per-sub starting states
  {
    float cur = s_in_blk;
#pragma unroll
    for (int s8 = 0; s8 < 8; ++s8) {
      lsS[s8][tid] = cur;
      cur = dB * cur + lsP[s8][tid];
    }
  }
  (void)dc;
  __syncthreads();

  // ---- Phase 3: recompute states, y = r*(state+v), in-place over k.
  float st[8];
#pragma unroll
  for (int jj = 0; jj < 8; ++jj) st[jj] = lsS[sub][c0 + jj];
#pragma unroll 2
  for (int i = 0; i < 32; ++i) {
    const size_t off = base + (size_t)i * 256;
    short8 kv = *reinterpret_cast<const short8*>(k + off);
    short8 vv = *reinterpret_cast<const short8*>(v + off);
    short8 rv = *reinterpret_cast<const short8*>(r + off);
    short8 y;
#pragma unroll
    for (int jj = 0; jj < 8; ++jj) {
      st[jj] = st[jj] * d[jj] + bf2f((unsigned short)kv[jj]);
      const float yj = bf2f((unsigned short)rv[jj]) * (st[jj] + bf2f((unsigned short)vv[jj]));
      y[jj] = (short)f2bf(yj);
    }
    *reinterpret_cast<short8*>(k + off) = y;
  }
}

// ---------------------------------------------------------------------------
extern "C" void kernel_launch(void* const* d_in, const int* in_sizes, int n_in,
                              void* d_out, int out_size, void* d_ws, size_t ws_size,
                              hipStream_t stream) {
  const float* x   = (const float*)d_in[0];
  const float* td  = (const float*)d_in[1];
  const float* Wk  = (const float*)d_in[2];
  const float* Wv  = (const float*)d_in[3];
  const float* Wr  = (const float*)d_in[4];
  const float* Wo  = (const float*)d_in[5];
  const float* lnw = (const float*)d_in[6];
  const float* lnb = (const float*)d_in[7];
  float* out = (float*)d_out;

  const size_t M = 131072;  // B*N
  const int C = 256;

  char* ws = (char*)d_ws;
  size_t off = 0;
  auto alloc = [&](size_t bytes) -> char* {
    char* p = ws + off;
    off += (bytes + 255) & ~(size_t)255;
    return p;
  };
  unsigned short* xn   = (unsigned short*)alloc(M * C * 2);
  unsigned short* kbuf = (unsigned short*)alloc(M * C * 2);  // later holds y
  unsigned short* vbuf = (unsigned short*)alloc(M * C * 2);
  unsigned short* rbuf = (unsigned short*)alloc(M * C * 2);
  unsigned short* Wkvr = (unsigned short*)alloc(768 * 256 * 2);
  unsigned short* Wob  = (unsigned short*)alloc(256 * 256 * 2);
  float* carryA  = (float*)alloc(512 * 256 * 4);
  float* prefixP = (float*)alloc(512 * 256 * 4);
  int*   flags   = (int*)alloc(512 * 4);
  (void)ws_size; (void)in_sizes; (void)n_in; (void)out_size;

  k1_fused<<<dim3(33793), dim3(256), 0, stream>>>(
      x, lnw, lnb, Wk, Wv, Wr, Wo, xn, Wkvr, Wob, flags);
  gemm_bt<0, 6><<<dim3(6144), dim3(256), 0, stream>>>(
      xn, Wkvr, kbuf, vbuf, rbuf, nullptr);
  scan_fused<<<dim3(512), dim3(256), 0, stream>>>(
      kbuf, vbuf, rbuf, td, carryA, prefixP, flags);
  gemm_bt<1, 2><<<dim3(2048), dim3(256), 0, stream>>>(
      kbuf, Wob, nullptr, nullptr, nullptr, out);
}